// Round 6
// baseline (126.147 us; speedup 1.0000x reference)
//
#include <hip/hip_runtime.h>
#include <hip/hip_bf16.h>
#include <hip/hip_fp16.h>

#define DD  256
#define HWD 1024
#define NN  32768
#define KK  1024
#define ZQ_SIZE (NN*DD)
#define IDX_OFF ZQ_SIZE
#define LOSS_OFF (ZQ_SIZE + NN)

// scratch layout (bytes) inside the z_q region of d_out (overwritten by gather)
#define CBH_OFF    0                    // fp16 codebook, 512 KB
#define CNORM_OFF  (KK*DD*2)            // 512 KB
#define ROWREC_OFF (CNORM_OFF + KK*4)   // rowrec: 8 floats/row, 1 MB

#define TH_REFINE 0.2f
#define LOSS_SCALE (0.25f / (float)ZQ_SIZE)

typedef __attribute__((ext_vector_type(8))) _Float16 h16x8;
typedef __attribute__((ext_vector_type(4))) float f32x4;

__device__ __forceinline__ void gload16(const void* g, void* l) {
    __builtin_amdgcn_global_load_lds(
        (const __attribute__((address_space(1))) void*)g,
        (__attribute__((address_space(3))) void*)l, 16, 0, 0);
}

// ---------------------------------------------------------------------------
// A: codebook -> fp16 + exact fp32 row norms
__global__ __launch_bounds__(256)
void vq_prep_kernel(const float* __restrict__ cb, unsigned char* __restrict__ scratch) {
    _Float16* cbh = (_Float16*)(scratch + CBH_OFF);
    float* cn = (float*)(scratch + CNORM_OFF);
    int t = threadIdx.x;
    int row = blockIdx.x * 16 + (t >> 4);   // grid 64
    int dq  = t & 15;
    const float* rp = cb + (size_t)row * DD + dq * 16;
    float nrm = 0.f;
    __attribute__((aligned(16))) _Float16 h[16];
#pragma unroll
    for (int i = 0; i < 4; ++i) {
        float4 v = *(const float4*)(rp + i * 4);
        float xs[4] = {v.x, v.y, v.z, v.w};
#pragma unroll
        for (int j = 0; j < 4; ++j) {
            float x = xs[j];
            h[i * 4 + j] = (_Float16)x;
            nrm = fmaf(x, x, nrm);
        }
    }
    *(uint4*)&cbh[(size_t)row * DD + dq * 16]     = *(uint4*)&h[0];
    *(uint4*)&cbh[(size_t)row * DD + dq * 16 + 8] = *(uint4*)&h[8];
#pragma unroll
    for (int m = 1; m < 16; m <<= 1) nrm += __shfl_xor(nrm, m, 64);
    if (dq == 0) cn[row] = nrm;
}

// ---------------------------------------------------------------------------
// B: fp16 MFMA distance-argmin. 512 thr = 8 waves = 2 row-groups x 4 k-quarts;
// 64 rows/block, grid 512 -> 2 blocks/CU. Single-term S = zh . ch; per-slot
// top-2 -> per-row top-3 via LDS scan; also accumulates sum(z^2) for the loss.
__global__ __launch_bounds__(512, 4)
void vq_mfma_argmin_kernel(const float* __restrict__ z, unsigned char* __restrict__ scratch,
                           float* __restrict__ lossp) {
    const unsigned char* cbh_b = scratch + CBH_OFF;
    const float* cn_g = (const float*)(scratch + CNORM_OFF);
    float* rowrec = (float*)(scratch + ROWREC_OFF);

    __shared__ char smem[65536];             // cbuf (2x32KB) then scan scratch
    short* cbuf0 = (short*)smem;             // [64 codes][256 d] fp16, swizzled
    short* cbuf1 = (short*)(smem + 32768);

    const int t    = threadIdx.x;
    const int w    = t >> 6;
    const int lane = t & 63;
    const int ln15 = lane & 15;
    const int lh   = lane >> 4;
    const int g    = w >> 2;         // row-group 0..1 (32 rows each)
    const int kh   = w & 3;          // code-quarter of each 64-code tile

    const int n0  = blockIdx.x * 64;
    const int b   = n0 >> 10;
    const int hw0 = n0 & 1023;

    // staging constants (gload16: per-lane source, wave-uniform LDS dest)
    const int ksub  = lane >> 5;
    const int chunk = lane & 31;

    // B-read constants
    const int klr   = kh * 16 + ln15;        // code row within tile
    const int rbase = klr * 256;             // shorts
    const int rxor  = (klr & 7) << 3;

    // ---- prologue: stage tile 0
#pragma unroll
    for (int si = 0; si < 4; ++si) {
        int gi = w * 4 + si;
        int kl = gi * 2 + ksub;
        const unsigned char* src = cbh_b + (size_t)kl * 512 + ((chunk ^ (kl & 7)) << 4);
        gload16(src, cbuf0 + (gi * 2) * 256);
    }

    // z A-fragments (fp16) + sum(z^2) contribution
    h16x8 ah[2][8];
    {
        float zsq = 0.f;
        const float* zcol = z + (size_t)b * DD * HWD + hw0 + g * 32 + ln15;
#pragma unroll
        for (int nf = 0; nf < 2; ++nf) {
            const float* zp = zcol + nf * 16;
#pragma unroll
            for (int ds = 0; ds < 8; ++ds) {
                const int d0 = ds * 32 + lh * 8;
#pragma unroll
                for (int j = 0; j < 8; ++j) {
                    float x = zp[(size_t)(d0 + j) * HWD];
                    ah[nf][ds][j] = (_Float16)x;
                    zsq = fmaf(x, x, zsq);
                }
            }
        }
#pragma unroll
        for (int m = 1; m < 64; m <<= 1) zsq += __shfl_xor(zsq, m, 64);
        if (kh == 0 && lane == 0) atomicAdd(lossp, zsq * LOSS_SCALE);  // rows counted once
    }
    __syncthreads();

    float v1[8], k1f[8], v2[8], k2f[8];
#pragma unroll
    for (int s = 0; s < 8; ++s) { v1[s] = 3e38f; v2[s] = 3e38f; k1f[s] = 0.f; k2f[s] = 0.f; }

    for (int kt = 0; kt < 16; ++kt) {
        short* cur = (kt & 1) ? cbuf1 : cbuf0;
        short* nxt = (kt & 1) ? cbuf0 : cbuf1;
        if (kt < 15) {                       // prefetch next 64-code tile
#pragma unroll
            for (int si = 0; si < 4; ++si) {
                int gi = w * 4 + si;
                int kl = gi * 2 + ksub;
                const unsigned char* src = cbh_b
                    + (size_t)((kt + 1) * 64 + kl) * 512 + ((chunk ^ (kl & 7)) << 4);
                gload16(src, nxt + (gi * 2) * 256);
            }
        }

        const int   kg  = kt * 64 + kh * 16 + ln15;
        const float cnv = cn_g[kg];          // hoisted above MFMA phase
        const float kgf = (float)kg;

        f32x4 acc0 = {0.f, 0.f, 0.f, 0.f};
        f32x4 acc1 = {0.f, 0.f, 0.f, 0.f};
#pragma unroll
        for (int ds = 0; ds < 8; ++ds) {
            const int ib = rbase + ((ds * 32 + lh * 8) ^ rxor);
            h16x8 bh = *(const h16x8*)&cur[ib];
            acc0 = __builtin_amdgcn_mfma_f32_16x16x32_f16(ah[0][ds], bh, acc0, 0, 0, 0);
            acc1 = __builtin_amdgcn_mfma_f32_16x16x32_f16(ah[1][ds], bh, acc1, 0, 0, 0);
        }

        // per-slot top-2 (strict < : first-min within ascending kg)
#pragma unroll
        for (int s = 0; s < 8; ++s) {
            float a = (s < 4) ? acc0[s] : acc1[s - 4];
            float dist = fmaf(-2.f, a, cnv);
            bool b1 = dist < v1[s];
            bool b2 = dist < v2[s];
            v2[s]  = b1 ? v1[s]  : (b2 ? dist : v2[s]);
            k2f[s] = b1 ? k1f[s] : (b2 ? kgf  : k2f[s]);
            v1[s]  = b1 ? dist : v1[s];
            k1f[s] = b1 ? kgf  : k1f[s];
        }
        __syncthreads();   // buffer handoff (prefetch had the whole compute phase)
    }

    // ---- per-row top-3 merge via LDS scan (cbuf is dead; alias it)
    float* redv = (float*)smem;              // [128 lists][64 rows]
    float* redk = redv + 128 * 64;           // second 32 KB
#pragma unroll
    for (int s = 0; s < 8; ++s) {
        int nf = s >> 2, r = s & 3;
        int rowb = g * 32 + nf * 16 + lh * 4 + r;   // C layout: row = lh*4+reg
        int list = kh * 16 + ln15;
        redv[list * 64 + rowb]        = v1[s];
        redk[list * 64 + rowb]        = k1f[s];
        redv[(64 + list) * 64 + rowb] = v2[s];
        redk[(64 + list) * 64 + rowb] = k2f[s];
    }
    __syncthreads();

    // stage 1: 512 threads, each scans 16 of the 128 entries for one row
    const int p = t >> 6, row = t & 63;
    float w1 = 3e38f, w2 = 3e38f, w3 = 3e38f, c1 = 0.f, c2 = 0.f, c3 = 0.f;
#pragma unroll
    for (int q = 0; q < 16; ++q) {
        int i = p * 16 + q;
        float v  = redv[i * 64 + row];
        float kf = redk[i * 64 + row];
        bool lt1 = (v < w1) || (v == w1 && kf < c1);
        bool lt2 = (v < w2) || (v == w2 && kf < c2);
        bool lt3 = (v < w3) || (v == w3 && kf < c3);
        w3 = lt2 ? w2 : (lt3 ? v : w3);  c3 = lt2 ? c2 : (lt3 ? kf : c3);
        w2 = lt1 ? w1 : (lt2 ? v : w2);  c2 = lt1 ? c1 : (lt2 ? kf : c2);
        w1 = lt1 ? v : w1;               c1 = lt1 ? kf : c1;
    }
    __syncthreads();                         // all reads done before overwrite
    {   // partials: [8 p][64 rows][3] (v,k)
        float* pv = (float*)smem;            // 6 KB
        float* pk = pv + 8 * 64 * 3;         // 6 KB
        int base = (p * 64 + row) * 3;
        pv[base + 0] = w1; pk[base + 0] = c1;
        pv[base + 1] = w2; pk[base + 1] = c2;
        pv[base + 2] = w3; pk[base + 2] = c3;
    }
    __syncthreads();
    if (t < 64) {                            // stage 2: merge 8 partial top-3s
        const float* pv = (const float*)smem;
        const float* pk = pv + 8 * 64 * 3;
        float u1 = 3e38f, u2 = 3e38f, u3 = 3e38f, d1 = 0.f, d2 = 0.f, d3 = 0.f;
#pragma unroll
        for (int i = 0; i < 24; ++i) {
            int pp = i / 3, e = i % 3;
            float v  = pv[(pp * 64 + t) * 3 + e];
            float kf = pk[(pp * 64 + t) * 3 + e];
            bool lt1 = (v < u1) || (v == u1 && kf < d1);
            bool lt2 = (v < u2) || (v == u2 && kf < d2);
            bool lt3 = (v < u3) || (v == u3 && kf < d3);
            u3 = lt2 ? u2 : (lt3 ? v : u3);  d3 = lt2 ? d2 : (lt3 ? kf : d3);
            u2 = lt1 ? u1 : (lt2 ? v : u2);  d2 = lt1 ? d1 : (lt2 ? kf : d2);
            u1 = lt1 ? v : u1;               d1 = lt1 ? kf : d1;
        }
        float4 ra; ra.x = u1; ra.y = d1; ra.z = u2; ra.w = d2;
        float4 rb; rb.x = u3; rb.y = d3; rb.z = 0.f; rb.w = 0.f;
        *(float4*)&rowrec[(size_t)(n0 + t) * 8]     = ra;
        *(float4*)&rowrec[(size_t)(n0 + t) * 8 + 4] = rb;
    }
}

// ---------------------------------------------------------------------------
// R: flagged rows (gap <= TH) -> exact fp32 recheck of top-3; also accumulates
// sum of chosen v1 (= dist - ||z||^2) for the commitment loss.
__global__ __launch_bounds__(256)
void vq_refine_kernel(const float* __restrict__ z, const float* __restrict__ cb,
                      const unsigned char* __restrict__ scratch, float* __restrict__ idx_out,
                      float* __restrict__ lossp) {
    const float* rowrec = (const float*)(scratch + ROWREC_OFF);
    const float* cn_g = (const float*)(scratch + CNORM_OFF);
    int n = blockIdx.x * 256 + threadIdx.x;   // grid 128
    int lane = threadIdx.x & 63;
    float4 ra = *(const float4*)&rowrec[(size_t)n * 8];
    float4 rb = *(const float4*)&rowrec[(size_t)n * 8 + 4];
    bool flag = (ra.z - ra.x) <= TH_REFINE;
    float lp = 0.f;
    if (!flag) { idx_out[n] = ra.y; lp = ra.x; }
    unsigned long long mask = __ballot(flag);
    while (mask) {
        int li = __ffsll(mask) - 1;
        mask &= mask - 1;
        int nn  = __shfl(n, li);
        int kk1 = (int)__shfl(ra.y, li);
        int kk2 = (int)__shfl(ra.w, li);
        int kk3 = (int)__shfl(rb.y, li);
        int bb = nn >> 10, hw = nn & 1023;
        const float* zp  = z  + (size_t)bb * DD * HWD + hw;
        const float* c1p = cb + (size_t)kk1 * DD;
        const float* c2p = cb + (size_t)kk2 * DD;
        const float* c3p = cb + (size_t)kk3 * DD;
        float s1 = 0.f, s2 = 0.f, s3 = 0.f;
#pragma unroll
        for (int j = 0; j < 4; ++j) {
            int d = lane + 64 * j;
            float zv = zp[(size_t)d * HWD];
            s1 = fmaf(zv, c1p[d], s1);
            s2 = fmaf(zv, c2p[d], s2);
            s3 = fmaf(zv, c3p[d], s3);
        }
#pragma unroll
        for (int m = 32; m >= 1; m >>= 1) {
            s1 += __shfl_xor(s1, m, 64);
            s2 += __shfl_xor(s2, m, 64);
            s3 += __shfl_xor(s3, m, 64);
        }
        float e1 = cn_g[kk1] - 2.f * s1;
        float e2 = cn_g[kk2] - 2.f * s2;
        float e3 = cn_g[kk3] - 2.f * s3;
        float dch = e1; int kch = kk1;
        if (e2 < dch || (e2 == dch && kk2 < kch)) { dch = e2; kch = kk2; }
        if (e3 < dch || (e3 == dch && kk3 < kch)) { dch = e3; kch = kk3; }
        if (lane == 0) { idx_out[nn] = (float)kch; lp += dch; }
    }
    // block loss reduction
#pragma unroll
    for (int m = 32; m >= 1; m >>= 1) lp += __shfl_xor(lp, m, 64);
    __shared__ float bl[4];
    if (lane == 0) bl[threadIdx.x >> 6] = lp;
    __syncthreads();
    if (threadIdx.x == 0)
        atomicAdd(lossp, (bl[0] + bl[1] + bl[2] + bl[3]) * LOSS_SCALE);
}

// ---------------------------------------------------------------------------
// C: pure gather z_q = codebook[idx] (tiled via LDS, coalesced writes)
__global__ __launch_bounds__(256)
void vq_gather_kernel(const float* __restrict__ cb, float* __restrict__ out) {
    const float* idxf = out + IDX_OFF;
    __shared__ float crow[64][257];
    __shared__ int kidx[64];
    int t = threadIdx.x;
    int w = t >> 6, lane = t & 63;
    int n0 = blockIdx.x * 64;                      // grid 512
    int b = n0 >> 10, hw0 = n0 & 1023;
    if (t < 64) kidx[t] = (int)idxf[n0 + t];
    __syncthreads();
    for (int i = 0; i < 16; ++i) {                 // 64 code rows, coalesced
        int r = w * 16 + i;
        int k = kidx[r];
        float4 v = *(const float4*)(cb + (size_t)k * DD + lane * 4);
        crow[r][lane * 4 + 0] = v.x; crow[r][lane * 4 + 1] = v.y;
        crow[r][lane * 4 + 2] = v.z; crow[r][lane * 4 + 3] = v.w;
    }
    __syncthreads();
    const int zph = t >> 6, hwl = t & 63;
#pragma unroll 4
    for (int dd = 0; dd < 64; ++dd) {
        int d = dd * 4 + zph;
        size_t o = (size_t)b * (DD * HWD) + (size_t)d * HWD + hw0 + hwl;
        out[o] = crow[hwl][d];
    }
}

// ---------------------------------------------------------------------------
extern "C" void kernel_launch(void* const* d_in, const int* in_sizes, int n_in,
                              void* d_out, int out_size, void* d_ws, size_t ws_size,
                              hipStream_t stream) {
    const float* z  = (const float*)d_in[0];
    const float* cb = (const float*)d_in[1];
    float* out = (float*)d_out;
    unsigned char* scratch = (unsigned char*)d_out;   // z_q region, overwritten by gather

    hipMemsetAsync((void*)(out + LOSS_OFF), 0, sizeof(float), stream);

    vq_prep_kernel<<<64, 256, 0, stream>>>(cb, scratch);
    vq_mfma_argmin_kernel<<<512, 512, 0, stream>>>(z, scratch, out + LOSS_OFF);
    vq_refine_kernel<<<128, 256, 0, stream>>>(z, cb, scratch, out + IDX_OFF, out + LOSS_OFF);
    vq_gather_kernel<<<512, 256, 0, stream>>>(cb, out);
}

// Round 7
// 94.637 us; speedup vs baseline: 1.3330x; 1.3330x over previous
//
#include <hip/hip_runtime.h>
#include <hip/hip_bf16.h>
#include <hip/hip_fp16.h>

#define DD  256
#define HWD 1024
#define NN  32768
#define KK  1024
#define ZQ_SIZE (NN*DD)
#define IDX_OFF ZQ_SIZE
#define LOSS_OFF (ZQ_SIZE + NN)

// scratch layout (bytes) inside the z_q region of d_out (overwritten by gather)
#define CBH_OFF    0                    // fp16 codebook, 512 KB
#define CNORM_OFF  (KK*DD*2)            // 512 KB
#define ROWREC_OFF (CNORM_OFF + KK*4)   // rowrec: 8 floats/row, 1 MB

#define TH_REFINE 0.2f
#define LOSS_SCALE (0.25f / (float)ZQ_SIZE)

typedef __attribute__((ext_vector_type(8))) _Float16 h16x8;
typedef __attribute__((ext_vector_type(4))) float f32x4;

__device__ __forceinline__ void gload16(const void* g, void* l) {
    __builtin_amdgcn_global_load_lds(
        (const __attribute__((address_space(1))) void*)g,
        (__attribute__((address_space(3))) void*)l, 16, 0, 0);
}

// ---------------------------------------------------------------------------
// A: codebook -> fp16 + exact fp32 row norms
__global__ __launch_bounds__(256)
void vq_prep_kernel(const float* __restrict__ cb, unsigned char* __restrict__ scratch) {
    _Float16* cbh = (_Float16*)(scratch + CBH_OFF);
    float* cn = (float*)(scratch + CNORM_OFF);
    int t = threadIdx.x;
    int row = blockIdx.x * 16 + (t >> 4);   // grid 64
    int dq  = t & 15;
    const float* rp = cb + (size_t)row * DD + dq * 16;
    float nrm = 0.f;
    __attribute__((aligned(16))) _Float16 h[16];
#pragma unroll
    for (int i = 0; i < 4; ++i) {
        float4 v = *(const float4*)(rp + i * 4);
        float xs[4] = {v.x, v.y, v.z, v.w};
#pragma unroll
        for (int j = 0; j < 4; ++j) {
            float x = xs[j];
            h[i * 4 + j] = (_Float16)x;
            nrm = fmaf(x, x, nrm);
        }
    }
    *(uint4*)&cbh[(size_t)row * DD + dq * 16]     = *(uint4*)&h[0];
    *(uint4*)&cbh[(size_t)row * DD + dq * 16 + 8] = *(uint4*)&h[8];
#pragma unroll
    for (int m = 1; m < 16; m <<= 1) nrm += __shfl_xor(nrm, m, 64);
    if (dq == 0) cn[row] = nrm;
}

// ---------------------------------------------------------------------------
// B: fp16 MFMA distance-argmin. 512 thr = 8 waves = 4 row-groups (16 rows)
// x 2 k-halves; 64 rows/block, grid 512 -> 2 blocks/CU pinned via
// amdgpu_waves_per_eu(4,4) (R6 lesson: (512,4) let the allocator squeeze to
// 64 VGPRs and scratch-spill; 4,4 grants the full 128-reg budget).
// Single-term S = zh . ch; per-slot top-2 -> per-row top-3 via LDS scan;
// also accumulates sum(z^2) for the loss.
__global__ __launch_bounds__(512) __attribute__((amdgpu_waves_per_eu(4, 4)))
void vq_mfma_argmin_kernel(const float* __restrict__ z, unsigned char* __restrict__ scratch,
                           float* __restrict__ lossp) {
    const unsigned char* cbh_b = scratch + CBH_OFF;
    const float* cn_g = (const float*)(scratch + CNORM_OFF);
    float* rowrec = (float*)(scratch + ROWREC_OFF);

    __shared__ char smem[32768];             // 2x16KB cbuf; aliased by merge scratch
    short* cbuf0 = (short*)smem;             // [32 codes][256 d] fp16, swizzled
    short* cbuf1 = (short*)(smem + 16384);

    const int t     = threadIdx.x;
    const int w     = t >> 6;
    const int lane  = t & 63;
    const int ln15  = lane & 15;
    const int lh    = lane >> 4;
    const int g     = w >> 1;        // row-group 0..3 (16 rows each)
    const int khalf = w & 1;         // which 16 codes of each 32-code tile

    const int n0  = blockIdx.x * 64;
    const int b   = n0 >> 10;
    const int hw0 = n0 & 1023;

    // staging constants (gload16: per-lane source, wave-uniform LDS dest)
    const int ksub  = lane >> 5;     // row within the 2-row slice
    const int chunk = lane & 31;     // 16B chunk within the 512B row

    // B-read constants
    const int klr   = khalf * 16 + ln15;     // code row within tile
    const int rbase = klr * 256;             // shorts
    const int rxor  = (klr & 7) << 3;        // swizzle (short units)

    // ---- prologue: stage tile 0 (16 KB: 16 slices of 1 KB, 2 per wave)
#pragma unroll
    for (int si = 0; si < 2; ++si) {
        int gi = w * 2 + si;                 // 0..15
        int kl = gi * 2 + ksub;              // 0..31
        const unsigned char* src = cbh_b + (size_t)kl * 512 + ((chunk ^ (kl & 7)) << 4);
        gload16(src, cbuf0 + gi * 2 * 256);
    }

    // z A-fragments (fp16) + sum(z^2) contribution
    h16x8 ah[8];
    {
        float zsq = 0.f;
        const float* zp = z + (size_t)b * DD * HWD + hw0 + g * 16 + ln15;
#pragma unroll
        for (int ds = 0; ds < 8; ++ds) {
            const int d0 = ds * 32 + lh * 8;
#pragma unroll
            for (int j = 0; j < 8; ++j) {
                float x = zp[(size_t)(d0 + j) * HWD];
                ah[ds][j] = (_Float16)x;
                zsq = fmaf(x, x, zsq);
            }
        }
#pragma unroll
        for (int m = 1; m < 64; m <<= 1) zsq += __shfl_xor(zsq, m, 64);
        if (khalf == 0 && lane == 0) atomicAdd(lossp, zsq * LOSS_SCALE);  // rows counted once
    }
    __syncthreads();

    float v1[4], k1f[4], v2[4], k2f[4];
#pragma unroll
    for (int s = 0; s < 4; ++s) { v1[s] = 3e38f; v2[s] = 3e38f; k1f[s] = 0.f; k2f[s] = 0.f; }

    for (int kt = 0; kt < 32; ++kt) {
        short* cur = (kt & 1) ? cbuf1 : cbuf0;
        short* nxt = (kt & 1) ? cbuf0 : cbuf1;
        if (kt < 31) {                       // prefetch next 32-code tile
#pragma unroll
            for (int si = 0; si < 2; ++si) {
                int gi = w * 2 + si;
                int kl = gi * 2 + ksub;
                const unsigned char* src = cbh_b
                    + (size_t)((kt + 1) * 32 + kl) * 512 + ((chunk ^ (kl & 7)) << 4);
                gload16(src, nxt + gi * 2 * 256);
            }
        }

        const int   kg  = kt * 32 + khalf * 16 + ln15;
        const float cnv = cn_g[kg];          // hoisted above MFMA phase
        const float kgf = (float)kg;

        // 4 independent accumulator chains (depth 2) over the 8 d-chunks
        f32x4 acc[4];
#pragma unroll
        for (int c = 0; c < 4; ++c) acc[c] = {0.f, 0.f, 0.f, 0.f};
#pragma unroll
        for (int ds = 0; ds < 8; ++ds) {
            const int ib = rbase + ((ds * 32 + lh * 8) ^ rxor);
            h16x8 bh = *(const h16x8*)&cur[ib];
            acc[ds & 3] = __builtin_amdgcn_mfma_f32_16x16x32_f16(ah[ds], bh, acc[ds & 3], 0, 0, 0);
        }
        f32x4 accs = (acc[0] + acc[1]) + (acc[2] + acc[3]);

        // per-slot top-2 (strict < : first-min within ascending kg)
#pragma unroll
        for (int s = 0; s < 4; ++s) {
            float dist = fmaf(-2.f, accs[s], cnv);
            bool b1 = dist < v1[s];
            bool b2 = dist < v2[s];
            v2[s]  = b1 ? v1[s]  : (b2 ? dist : v2[s]);
            k2f[s] = b1 ? k1f[s] : (b2 ? kgf  : k2f[s]);
            v1[s]  = b1 ? dist : v1[s];
            k1f[s] = b1 ? kgf  : k1f[s];
        }
        __syncthreads();   // buffer handoff (prefetch had the whole compute phase)
    }

    // ---- per-row top-3 merge via LDS scan (cbuf is dead; alias it)
    // 64 candidate lists per row: list = khalf*16+ln15 (entry 0) and +32 (entry 1)
    float* redv = (float*)smem;              // [64 lists][64 rows] = 16 KB
    float* redk = redv + 64 * 64;            // 16 KB
#pragma unroll
    for (int s = 0; s < 4; ++s) {
        int rowb = g * 16 + lh * 4 + s;      // C layout: row = lh*4+reg
        int list = khalf * 16 + ln15;
        redv[list * 64 + rowb]        = v1[s];
        redk[list * 64 + rowb]        = k1f[s];
        redv[(32 + list) * 64 + rowb] = v2[s];
        redk[(32 + list) * 64 + rowb] = k2f[s];
    }
    __syncthreads();

    // stage 1: 512 threads, each scans 8 of the 64 entries for one row
    const int p = t >> 6, row = t & 63;
    float w1 = 3e38f, w2 = 3e38f, w3 = 3e38f, c1 = 0.f, c2 = 0.f, c3 = 0.f;
#pragma unroll
    for (int q = 0; q < 8; ++q) {
        int i = p * 8 + q;
        float v  = redv[i * 64 + row];
        float kf = redk[i * 64 + row];
        bool lt1 = (v < w1) || (v == w1 && kf < c1);
        bool lt2 = (v < w2) || (v == w2 && kf < c2);
        bool lt3 = (v < w3) || (v == w3 && kf < c3);
        w3 = lt2 ? w2 : (lt3 ? v : w3);  c3 = lt2 ? c2 : (lt3 ? kf : c3);
        w2 = lt1 ? w1 : (lt2 ? v : w2);  c2 = lt1 ? c1 : (lt2 ? kf : c2);
        w1 = lt1 ? v : w1;               c1 = lt1 ? kf : c1;
    }
    __syncthreads();                         // all reads done before overwrite
    {   // partials: [8 p][64 rows][3] (v,k)
        float* pv = (float*)smem;            // 6 KB
        float* pk = pv + 8 * 64 * 3;         // 6 KB
        int base = (p * 64 + row) * 3;
        pv[base + 0] = w1; pk[base + 0] = c1;
        pv[base + 1] = w2; pk[base + 1] = c2;
        pv[base + 2] = w3; pk[base + 2] = c3;
    }
    __syncthreads();
    if (t < 64) {                            // stage 2: merge 8 partial top-3s
        const float* pv = (const float*)smem;
        const float* pk = pv + 8 * 64 * 3;
        float u1 = 3e38f, u2 = 3e38f, u3 = 3e38f, d1 = 0.f, d2 = 0.f, d3 = 0.f;
#pragma unroll
        for (int i = 0; i < 24; ++i) {
            int pp = i / 3, e = i % 3;
            float v  = pv[(pp * 64 + t) * 3 + e];
            float kf = pk[(pp * 64 + t) * 3 + e];
            bool lt1 = (v < u1) || (v == u1 && kf < d1);
            bool lt2 = (v < u2) || (v == u2 && kf < d2);
            bool lt3 = (v < u3) || (v == u3 && kf < d3);
            u3 = lt2 ? u2 : (lt3 ? v : u3);  d3 = lt2 ? d2 : (lt3 ? kf : d3);
            u2 = lt1 ? u1 : (lt2 ? v : u2);  d2 = lt1 ? d1 : (lt2 ? kf : d2);
            u1 = lt1 ? v : u1;               d1 = lt1 ? kf : d1;
        }
        float4 ra; ra.x = u1; ra.y = d1; ra.z = u2; ra.w = d2;
        float4 rb; rb.x = u3; rb.y = d3; rb.z = 0.f; rb.w = 0.f;
        *(float4*)&rowrec[(size_t)(n0 + t) * 8]     = ra;
        *(float4*)&rowrec[(size_t)(n0 + t) * 8 + 4] = rb;
    }
}

// ---------------------------------------------------------------------------
// R: flagged rows (gap <= TH) -> exact fp32 recheck of top-3; also accumulates
// sum of chosen v1 (= dist - ||z||^2) for the commitment loss.
__global__ __launch_bounds__(256)
void vq_refine_kernel(const float* __restrict__ z, const float* __restrict__ cb,
                      const unsigned char* __restrict__ scratch, float* __restrict__ idx_out,
                      float* __restrict__ lossp) {
    const float* rowrec = (const float*)(scratch + ROWREC_OFF);
    const float* cn_g = (const float*)(scratch + CNORM_OFF);
    int n = blockIdx.x * 256 + threadIdx.x;   // grid 128
    int lane = threadIdx.x & 63;
    float4 ra = *(const float4*)&rowrec[(size_t)n * 8];
    float4 rb = *(const float4*)&rowrec[(size_t)n * 8 + 4];
    bool flag = (ra.z - ra.x) <= TH_REFINE;
    float lp = 0.f;
    if (!flag) { idx_out[n] = ra.y; lp = ra.x; }
    unsigned long long mask = __ballot(flag);
    while (mask) {
        int li = __ffsll(mask) - 1;
        mask &= mask - 1;
        int nn  = __shfl(n, li);
        int kk1 = (int)__shfl(ra.y, li);
        int kk2 = (int)__shfl(ra.w, li);
        int kk3 = (int)__shfl(rb.y, li);
        int bb = nn >> 10, hw = nn & 1023;
        const float* zp  = z  + (size_t)bb * DD * HWD + hw;
        const float* c1p = cb + (size_t)kk1 * DD;
        const float* c2p = cb + (size_t)kk2 * DD;
        const float* c3p = cb + (size_t)kk3 * DD;
        float s1 = 0.f, s2 = 0.f, s3 = 0.f;
#pragma unroll
        for (int j = 0; j < 4; ++j) {
            int d = lane + 64 * j;
            float zv = zp[(size_t)d * HWD];
            s1 = fmaf(zv, c1p[d], s1);
            s2 = fmaf(zv, c2p[d], s2);
            s3 = fmaf(zv, c3p[d], s3);
        }
#pragma unroll
        for (int m = 32; m >= 1; m >>= 1) {
            s1 += __shfl_xor(s1, m, 64);
            s2 += __shfl_xor(s2, m, 64);
            s3 += __shfl_xor(s3, m, 64);
        }
        float e1 = cn_g[kk1] - 2.f * s1;
        float e2 = cn_g[kk2] - 2.f * s2;
        float e3 = cn_g[kk3] - 2.f * s3;
        float dch = e1; int kch = kk1;
        if (e2 < dch || (e2 == dch && kk2 < kch)) { dch = e2; kch = kk2; }
        if (e3 < dch || (e3 == dch && kk3 < kch)) { dch = e3; kch = kk3; }
        if (lane == 0) { idx_out[nn] = (float)kch; lp += dch; }
    }
    // block loss reduction
#pragma unroll
    for (int m = 32; m >= 1; m >>= 1) lp += __shfl_xor(lp, m, 64);
    __shared__ float bl[4];
    if (lane == 0) bl[threadIdx.x >> 6] = lp;
    __syncthreads();
    if (threadIdx.x == 0)
        atomicAdd(lossp, (bl[0] + bl[1] + bl[2] + bl[3]) * LOSS_SCALE);
}

// ---------------------------------------------------------------------------
// C: pure gather z_q = codebook[idx] (tiled via LDS, coalesced writes)
__global__ __launch_bounds__(256)
void vq_gather_kernel(const float* __restrict__ cb, float* __restrict__ out) {
    const float* idxf = out + IDX_OFF;
    __shared__ float crow[64][257];
    __shared__ int kidx[64];
    int t = threadIdx.x;
    int w = t >> 6, lane = t & 63;
    int n0 = blockIdx.x * 64;                      // grid 512
    int b = n0 >> 10, hw0 = n0 & 1023;
    if (t < 64) kidx[t] = (int)idxf[n0 + t];
    __syncthreads();
    for (int i = 0; i < 16; ++i) {                 // 64 code rows, coalesced
        int r = w * 16 + i;
        int k = kidx[r];
        float4 v = *(const float4*)(cb + (size_t)k * DD + lane * 4);
        crow[r][lane * 4 + 0] = v.x; crow[r][lane * 4 + 1] = v.y;
        crow[r][lane * 4 + 2] = v.z; crow[r][lane * 4 + 3] = v.w;
    }
    __syncthreads();
    const int zph = t >> 6, hwl = t & 63;
#pragma unroll 4
    for (int dd = 0; dd < 64; ++dd) {
        int d = dd * 4 + zph;
        size_t o = (size_t)b * (DD * HWD) + (size_t)d * HWD + hw0 + hwl;
        out[o] = crow[hwl][d];
    }
}

// ---------------------------------------------------------------------------
extern "C" void kernel_launch(void* const* d_in, const int* in_sizes, int n_in,
                              void* d_out, int out_size, void* d_ws, size_t ws_size,
                              hipStream_t stream) {
    const float* z  = (const float*)d_in[0];
    const float* cb = (const float*)d_in[1];
    float* out = (float*)d_out;
    unsigned char* scratch = (unsigned char*)d_out;   // z_q region, overwritten by gather

    hipMemsetAsync((void*)(out + LOSS_OFF), 0, sizeof(float), stream);

    vq_prep_kernel<<<64, 256, 0, stream>>>(cb, scratch);
    vq_mfma_argmin_kernel<<<512, 512, 0, stream>>>(z, scratch, out + LOSS_OFF);
    vq_refine_kernel<<<128, 256, 0, stream>>>(z, cb, scratch, out + IDX_OFF, out + LOSS_OFF);
    vq_gather_kernel<<<512, 256, 0, stream>>>(cb, out);
}

// Round 8
// 80.825 us; speedup vs baseline: 1.5607x; 1.1709x over previous
//
#include <hip/hip_runtime.h>
#include <hip/hip_bf16.h>
#include <hip/hip_fp16.h>

#define DD  256
#define HWD 1024
#define NN  32768
#define KK  1024
#define ZQ_SIZE (NN*DD)
#define IDX_OFF ZQ_SIZE
#define LOSS_OFF (ZQ_SIZE + NN)

// scratch layout (bytes) inside the z_q region of d_out (overwritten by gather)
#define CBH_OFF    0                    // fp16 codebook, 512 KB
#define CNORM_OFF  (KK*DD*2)            // 512 KB
#define ROWREC_OFF (CNORM_OFF + KK*4)   // rowrec: 8 floats/row, 1 MB

#define TH_REFINE 0.2f
#define LOSS_SCALE (0.25f / (float)ZQ_SIZE)

typedef __attribute__((ext_vector_type(8))) _Float16 h16x8;
typedef __attribute__((ext_vector_type(4))) float f32x4;

__device__ __forceinline__ void gload16(const void* g, void* l) {
    __builtin_amdgcn_global_load_lds(
        (const __attribute__((address_space(1))) void*)g,
        (__attribute__((address_space(3))) void*)l, 16, 0, 0);
}

// ---------------------------------------------------------------------------
// A: codebook -> fp16 + exact fp32 row norms
__global__ __launch_bounds__(256)
void vq_prep_kernel(const float* __restrict__ cb, unsigned char* __restrict__ scratch) {
    _Float16* cbh = (_Float16*)(scratch + CBH_OFF);
    float* cn = (float*)(scratch + CNORM_OFF);
    int t = threadIdx.x;
    int row = blockIdx.x * 16 + (t >> 4);   // grid 64
    int dq  = t & 15;
    const float* rp = cb + (size_t)row * DD + dq * 16;
    float nrm = 0.f;
    __attribute__((aligned(16))) _Float16 h[16];
#pragma unroll
    for (int i = 0; i < 4; ++i) {
        float4 v = *(const float4*)(rp + i * 4);
        float xs[4] = {v.x, v.y, v.z, v.w};
#pragma unroll
        for (int j = 0; j < 4; ++j) {
            float x = xs[j];
            h[i * 4 + j] = (_Float16)x;
            nrm = fmaf(x, x, nrm);
        }
    }
    *(uint4*)&cbh[(size_t)row * DD + dq * 16]     = *(uint4*)&h[0];
    *(uint4*)&cbh[(size_t)row * DD + dq * 16 + 8] = *(uint4*)&h[8];
#pragma unroll
    for (int m = 1; m < 16; m <<= 1) nrm += __shfl_xor(nrm, m, 64);
    if (dq == 0) cn[row] = nrm;
}

// ---------------------------------------------------------------------------
// B: fp16 MFMA distance-argmin, counted-vmcnt pipeline.
// 256 thr = 4 waves = 2 row-groups (32 rows, nf=2) x 2 k-halves; 64 rows/blk,
// grid 512 -> 2 blocks/CU. 4 tile buffers (32 codes each), prefetch 3 deep,
// raw s_barrier + s_waitcnt vmcnt(8) keeps loads in flight across barriers.
__global__ __launch_bounds__(256) __attribute__((amdgpu_waves_per_eu(2, 2)))
void vq_mfma_argmin_kernel(const float* __restrict__ z, unsigned char* __restrict__ scratch,
                           float* __restrict__ lossp) {
    const unsigned char* cbh_b = scratch + CBH_OFF;
    const float* cn_g = (const float*)(scratch + CNORM_OFF);
    float* rowrec = (float*)(scratch + ROWREC_OFF);

    __shared__ __attribute__((aligned(16))) short bufs[4 * 8192];  // 64 KB
    __shared__ float cn_l[KK];                                     // 4 KB

    const int t    = threadIdx.x;
    const int w    = t >> 6;
    const int lane = t & 63;
    const int ln15 = lane & 15;
    const int lh   = lane >> 4;
    const int g     = w >> 1;        // row-group 0..1 (32 rows each)
    const int khalf = w & 1;         // 16-code half of each 32-code tile

    const int n0  = blockIdx.x * 64;
    const int b   = n0 >> 10;
    const int hw0 = n0 & 1023;

    // staging lane constants (gload16: per-lane source, wave-uniform LDS dest)
    const int ksub  = lane >> 5;
    const int chunk = lane & 31;

    // B-read constants
    const int klr   = khalf * 16 + ln15;     // code row within 32-code tile
    const int rbase = klr * 256;             // shorts
    const int rxor  = (klr & 7) << 3;        // swizzle (short units)

    // ---- cn -> LDS (visible after the prologue __syncthreads)
    *(float4*)&cn_l[t * 4] = *(const float4*)(cn_g + t * 4);

    // ---- z A-fragments (nf=2, fp16) + sum(z^2) for the loss
    h16x8 ah[2][8];
    {
        float zsq = 0.f;
        const float* zc = z + (size_t)b * DD * HWD + hw0 + g * 32 + ln15;
#pragma unroll
        for (int nf = 0; nf < 2; ++nf) {
            const float* zp = zc + nf * 16;
#pragma unroll
            for (int ds = 0; ds < 8; ++ds) {
                const int d0 = ds * 32 + lh * 8;
#pragma unroll
                for (int j = 0; j < 8; ++j) {
                    float x = zp[(size_t)(d0 + j) * HWD];
                    ah[nf][ds][j] = (_Float16)x;
                    zsq = fmaf(x, x, zsq);
                }
            }
        }
#pragma unroll
        for (int m = 1; m < 64; m <<= 1) zsq += __shfl_xor(zsq, m, 64);
        if (khalf == 0 && lane == 0) atomicAdd(lossp, zsq * LOSS_SCALE);
    }
    __syncthreads();   // cn_l visible; drains all prologue vmem (vmcnt -> 0)

    // stage tile tt into bufs[tt&3]: 16 slices of 1KB, 4 per wave
    auto STAGE = [&](int tt) {
#pragma unroll
        for (int si = 0; si < 4; ++si) {
            int s  = w * 4 + si;
            int kl = s * 2 + ksub;
            const unsigned char* src = cbh_b
                + (size_t)(tt * 32 + kl) * 512 + ((chunk ^ (kl & 7)) << 4);
            gload16(src, &bufs[(tt & 3) * 8192 + s * 512]);
        }
    };

    float v1[8], k1f[8], v2[8], k2f[8];
#pragma unroll
    for (int s = 0; s < 8; ++s) { v1[s] = 3e38f; v2[s] = 3e38f; k1f[s] = 0.f; k2f[s] = 0.f; }

    auto COMPUTE = [&](int kt) {
        const short* cbt = &bufs[(kt & 3) * 8192];
        const float cnv = cn_l[kt * 32 + klr];
        const float kgf = (float)(kt * 32 + klr);
        f32x4 c0 = {0.f,0.f,0.f,0.f}, c1 = c0, c2 = c0, c3 = c0;
#pragma unroll
        for (int ds = 0; ds < 8; ds += 2) {
            const int ib0 = rbase + (((ds + 0) * 32 + lh * 8) ^ rxor);
            const int ib1 = rbase + (((ds + 1) * 32 + lh * 8) ^ rxor);
            h16x8 b0 = *(const h16x8*)&cbt[ib0];
            h16x8 b1 = *(const h16x8*)&cbt[ib1];
            c0 = __builtin_amdgcn_mfma_f32_16x16x32_f16(ah[0][ds + 0], b0, c0, 0, 0, 0);
            c2 = __builtin_amdgcn_mfma_f32_16x16x32_f16(ah[1][ds + 0], b0, c2, 0, 0, 0);
            c1 = __builtin_amdgcn_mfma_f32_16x16x32_f16(ah[0][ds + 1], b1, c1, 0, 0, 0);
            c3 = __builtin_amdgcn_mfma_f32_16x16x32_f16(ah[1][ds + 1], b1, c3, 0, 0, 0);
        }
        f32x4 s0 = c0 + c1, s1 = c2 + c3;
#pragma unroll
        for (int s = 0; s < 8; ++s) {
            float a = (s < 4) ? s0[s] : s1[s - 4];
            float dist = fmaf(-2.f, a, cnv);
            bool b1c = dist < v1[s];
            bool b2c = dist < v2[s];
            v2[s]  = b1c ? v1[s]  : (b2c ? dist : v2[s]);
            k2f[s] = b1c ? k1f[s] : (b2c ? kgf  : k2f[s]);
            v1[s]  = b1c ? dist : v1[s];
            k1f[s] = b1c ? kgf  : k1f[s];
        }
    };

    // prologue: 3 tiles in flight (12 loads)
    STAGE(0); STAGE(1); STAGE(2);

    // main loop: wait tile kt (8 = 2 newer tiles x 4 loads outstanding), sync,
    // issue kt+3 into the buffer retired at kt-1, compute kt.
    for (int kt = 0; kt < 29; ++kt) {
        asm volatile("s_waitcnt vmcnt(8)" ::: "memory");
        __builtin_amdgcn_sched_barrier(0);
        __builtin_amdgcn_s_barrier();
        __builtin_amdgcn_sched_barrier(0);
        STAGE(kt + 3);
        COMPUTE(kt);
    }
    // tail: no more staging; drain 8 -> 4 -> 0
    asm volatile("s_waitcnt vmcnt(8)" ::: "memory");
    __builtin_amdgcn_sched_barrier(0);
    __builtin_amdgcn_s_barrier();
    __builtin_amdgcn_sched_barrier(0);
    COMPUTE(29);
    asm volatile("s_waitcnt vmcnt(4)" ::: "memory");
    __builtin_amdgcn_sched_barrier(0);
    __builtin_amdgcn_s_barrier();
    __builtin_amdgcn_sched_barrier(0);
    COMPUTE(30);
    asm volatile("s_waitcnt vmcnt(0)" ::: "memory");
    __builtin_amdgcn_sched_barrier(0);
    __builtin_amdgcn_s_barrier();
    __builtin_amdgcn_sched_barrier(0);
    COMPUTE(31);

    // ---- per-row top-3 merge (alias bufs; padded stride 65 vs bank conflicts)
    __syncthreads();
    float* redv = (float*)bufs;              // [64 entries][stride 65] ~16.6 KB
    float* redk = redv + 64 * 65;            // ~16.6 KB
#pragma unroll
    for (int s = 0; s < 8; ++s) {
        int nf = s >> 2, r = s & 3;
        int rowb = g * 32 + nf * 16 + lh * 4 + r;   // C layout: row = lh*4+reg
        redv[klr * 65 + rowb]        = v1[s];
        redk[klr * 65 + rowb]        = k1f[s];
        redv[(32 + klr) * 65 + rowb] = v2[s];
        redk[(32 + klr) * 65 + rowb] = k2f[s];
    }
    __syncthreads();

    // stage 1: 256 threads, each scans 16 of the 64 entries for one row
    const int p = t >> 6, row = t & 63;
    float w1 = 3e38f, w2 = 3e38f, w3 = 3e38f, c1e = 0.f, c2e = 0.f, c3e = 0.f;
#pragma unroll
    for (int q = 0; q < 16; ++q) {
        int i = p * 16 + q;
        float v  = redv[i * 65 + row];
        float kf = redk[i * 65 + row];
        bool lt1 = (v < w1) || (v == w1 && kf < c1e);
        bool lt2 = (v < w2) || (v == w2 && kf < c2e);
        bool lt3 = (v < w3) || (v == w3 && kf < c3e);
        w3 = lt2 ? w2 : (lt3 ? v : w3);  c3e = lt2 ? c2e : (lt3 ? kf : c3e);
        w2 = lt1 ? w1 : (lt2 ? v : w2);  c2e = lt1 ? c1e : (lt2 ? kf : c2e);
        w1 = lt1 ? v : w1;               c1e = lt1 ? kf : c1e;
    }
    __syncthreads();
    {   // partials: [4 p][64 rows][3]
        float* pv = (float*)bufs;            // 3 KB
        float* pk = pv + 4 * 64 * 3;         // 3 KB
        int base = (p * 64 + row) * 3;
        pv[base + 0] = w1; pk[base + 0] = c1e;
        pv[base + 1] = w2; pk[base + 1] = c2e;
        pv[base + 2] = w3; pk[base + 2] = c3e;
    }
    __syncthreads();
    if (t < 64) {                            // stage 2: merge 4 partial top-3s
        const float* pv = (const float*)bufs;
        const float* pk = pv + 4 * 64 * 3;
        float u1 = 3e38f, u2 = 3e38f, u3 = 3e38f, d1 = 0.f, d2 = 0.f, d3 = 0.f;
#pragma unroll
        for (int i = 0; i < 12; ++i) {
            int pp = i / 3, e = i % 3;
            float v  = pv[(pp * 64 + t) * 3 + e];
            float kf = pk[(pp * 64 + t) * 3 + e];
            bool lt1 = (v < u1) || (v == u1 && kf < d1);
            bool lt2 = (v < u2) || (v == u2 && kf < d2);
            bool lt3 = (v < u3) || (v == u3 && kf < d3);
            u3 = lt2 ? u2 : (lt3 ? v : u3);  d3 = lt2 ? d2 : (lt3 ? kf : d3);
            u2 = lt1 ? u1 : (lt2 ? v : u2);  d2 = lt1 ? d1 : (lt2 ? kf : d2);
            u1 = lt1 ? v : u1;               d1 = lt1 ? kf : d1;
        }
        float4 ra; ra.x = u1; ra.y = d1; ra.z = u2; ra.w = d2;
        float4 rb; rb.x = u3; rb.y = d3; rb.z = 0.f; rb.w = 0.f;
        *(float4*)&rowrec[(size_t)(n0 + t) * 8]     = ra;
        *(float4*)&rowrec[(size_t)(n0 + t) * 8 + 4] = rb;
    }
}

// ---------------------------------------------------------------------------
// R: flagged rows (gap <= TH) -> exact fp32 recheck of top-3; also accumulates
// sum of chosen v1 (= dist - ||z||^2) for the commitment loss.
__global__ __launch_bounds__(256)
void vq_refine_kernel(const float* __restrict__ z, const float* __restrict__ cb,
                      const unsigned char* __restrict__ scratch, float* __restrict__ idx_out,
                      float* __restrict__ lossp) {
    const float* rowrec = (const float*)(scratch + ROWREC_OFF);
    const float* cn_g = (const float*)(scratch + CNORM_OFF);
    int n = blockIdx.x * 256 + threadIdx.x;   // grid 128
    int lane = threadIdx.x & 63;
    float4 ra = *(const float4*)&rowrec[(size_t)n * 8];
    float4 rb = *(const float4*)&rowrec[(size_t)n * 8 + 4];
    bool flag = (ra.z - ra.x) <= TH_REFINE;
    float lp = 0.f;
    if (!flag) { idx_out[n] = ra.y; lp = ra.x; }
    unsigned long long mask = __ballot(flag);
    while (mask) {
        int li = __ffsll(mask) - 1;
        mask &= mask - 1;
        int nn  = __shfl(n, li);
        int kk1 = (int)__shfl(ra.y, li);
        int kk2 = (int)__shfl(ra.w, li);
        int kk3 = (int)__shfl(rb.y, li);
        int bb = nn >> 10, hw = nn & 1023;
        const float* zp  = z  + (size_t)bb * DD * HWD + hw;
        const float* c1p = cb + (size_t)kk1 * DD;
        const float* c2p = cb + (size_t)kk2 * DD;
        const float* c3p = cb + (size_t)kk3 * DD;
        float s1 = 0.f, s2 = 0.f, s3 = 0.f;
#pragma unroll
        for (int j = 0; j < 4; ++j) {
            int d = lane + 64 * j;
            float zv = zp[(size_t)d * HWD];
            s1 = fmaf(zv, c1p[d], s1);
            s2 = fmaf(zv, c2p[d], s2);
            s3 = fmaf(zv, c3p[d], s3);
        }
#pragma unroll
        for (int m = 32; m >= 1; m >>= 1) {
            s1 += __shfl_xor(s1, m, 64);
            s2 += __shfl_xor(s2, m, 64);
            s3 += __shfl_xor(s3, m, 64);
        }
        float e1 = cn_g[kk1] - 2.f * s1;
        float e2 = cn_g[kk2] - 2.f * s2;
        float e3 = cn_g[kk3] - 2.f * s3;
        float dch = e1; int kch = kk1;
        if (e2 < dch || (e2 == dch && kk2 < kch)) { dch = e2; kch = kk2; }
        if (e3 < dch || (e3 == dch && kk3 < kch)) { dch = e3; kch = kk3; }
        if (lane == 0) { idx_out[nn] = (float)kch; lp += dch; }
    }
    // block loss reduction
#pragma unroll
    for (int m = 32; m >= 1; m >>= 1) lp += __shfl_xor(lp, m, 64);
    __shared__ float bl[4];
    if (lane == 0) bl[threadIdx.x >> 6] = lp;
    __syncthreads();
    if (threadIdx.x == 0)
        atomicAdd(lossp, (bl[0] + bl[1] + bl[2] + bl[3]) * LOSS_SCALE);
}

// ---------------------------------------------------------------------------
// C: pure gather z_q = codebook[idx] (tiled via LDS, coalesced writes)
__global__ __launch_bounds__(256)
void vq_gather_kernel(const float* __restrict__ cb, float* __restrict__ out) {
    const float* idxf = out + IDX_OFF;
    __shared__ float crow[64][257];
    __shared__ int kidx[64];
    int t = threadIdx.x;
    int w = t >> 6, lane = t & 63;
    int n0 = blockIdx.x * 64;                      // grid 512
    int b = n0 >> 10, hw0 = n0 & 1023;
    if (t < 64) kidx[t] = (int)idxf[n0 + t];
    __syncthreads();
    for (int i = 0; i < 16; ++i) {                 // 64 code rows, coalesced
        int r = w * 16 + i;
        int k = kidx[r];
        float4 v = *(const float4*)(cb + (size_t)k * DD + lane * 4);
        crow[r][lane * 4 + 0] = v.x; crow[r][lane * 4 + 1] = v.y;
        crow[r][lane * 4 + 2] = v.z; crow[r][lane * 4 + 3] = v.w;
    }
    __syncthreads();
    const int zph = t >> 6, hwl = t & 63;
#pragma unroll 4
    for (int dd = 0; dd < 64; ++dd) {
        int d = dd * 4 + zph;
        size_t o = (size_t)b * (DD * HWD) + (size_t)d * HWD + hw0 + hwl;
        out[o] = crow[hwl][d];
    }
}

// ---------------------------------------------------------------------------
extern "C" void kernel_launch(void* const* d_in, const int* in_sizes, int n_in,
                              void* d_out, int out_size, void* d_ws, size_t ws_size,
                              hipStream_t stream) {
    const float* z  = (const float*)d_in[0];
    const float* cb = (const float*)d_in[1];
    float* out = (float*)d_out;
    unsigned char* scratch = (unsigned char*)d_out;   // z_q region, overwritten by gather

    hipMemsetAsync((void*)(out + LOSS_OFF), 0, sizeof(float), stream);

    vq_prep_kernel<<<64, 256, 0, stream>>>(cb, scratch);
    vq_mfma_argmin_kernel<<<512, 256, 0, stream>>>(z, scratch, out + LOSS_OFF);
    vq_refine_kernel<<<128, 256, 0, stream>>>(z, cb, scratch, out + IDX_OFF, out + LOSS_OFF);
    vq_gather_kernel<<<512, 256, 0, stream>>>(cb, out);
}